// Round 13
// baseline (25.430 us; speedup 1.0000x reference)
//
#include <hip/hip_runtime.h>
#include <hip/hip_bf16.h>
#include <float.h>

typedef float f32x4 __attribute__((ext_vector_type(4)));
typedef int i32x4 __attribute__((ext_vector_type(4)));

// Kernel 1 (dense, t-major): argmax over vocab for ACTIVE (t,b) rows only,
// enumerated in (t, b) sorted order so concurrent waves read near-contiguous
// addresses (all active b at one t live in one 64KB slab).
// x layout: (seq_len, batch, vocab); row = t*batch + b.
// Task k: t s.t. S(t) <= k < S(t+1), S(t) = sum_b min(len_b, t);
//         b = (k - S(t))-th active b at time t (len_b > t), ascending.
// Intra-wave: 8 tasks/wave, 8 lanes/task; 3-step __shfl_xor reduce.
// Output ml stored TRANSPOSED: ml[b*seq_len + t]. Also fills tokens with -1.
// Requires batch <= 64 (lengths held one-per-lane).
__global__ __launch_bounds__(256) void ctc_argmax_dense(
    const float* __restrict__ x,
    int* __restrict__ ml,
    const int* __restrict__ lengths,
    int* __restrict__ tokens,
    int seq_len, int batch, int vocab) {
    const int nrows = seq_len * batch;

    // -1 fill of tokens (batch*seq_len ints), grid-strided (measured free).
    const int gtid = blockIdx.x * blockDim.x + threadIdx.x;
    const int gstride = gridDim.x * blockDim.x;
    for (int i = gtid; i < nrows; i += gstride) tokens[i] = -1;

    const int lane = threadIdx.x & 63;
    const int wave = blockIdx.x * (blockDim.x >> 6) + (threadIdx.x >> 6);
    const int k0 = wave * 8;

    const int lenL = (lane < batch) ? lengths[lane] : 0;

    // total = sum of lengths (wave reduce); inactive waves exit early.
    int total = lenL;
#pragma unroll
    for (int m = 1; m < 64; m <<= 1) total += __shfl_xor(total, m, 64);
    if (k0 >= total) return;

    // Binary search: largest t0 with S(t0) <= k0. S monotone, S(0)=0.
    int t0 = 0;
    int step = 1;
    while ((step << 1) <= seq_len) step <<= 1;
    for (; step; step >>= 1) {
        const int probe = t0 + step;
        if (probe <= seq_len) {
            int s = (lenL < probe) ? lenL : probe;
#pragma unroll
            for (int m = 1; m < 64; m <<= 1) s += __shfl_xor(s, m, 64);
            if (s <= k0) t0 = probe;
        }
    }
    // S_run = S(t0)
    int S_run = (lenL < t0) ? lenL : t0;
#pragma unroll
    for (int m = 1; m < 64; m <<= 1) S_run += __shfl_xor(S_run, m, 64);

    const int g = lane >> 3;    // task group 0..7
    const int sl = lane & 7;    // sub-lane within group
    const int k = k0 + g;
    const bool act = (k < total);

    // Walk t upward (uniform), latching each lane's (t, b) when its k falls
    // in [S(t), S(t)+A(t)). b = j-th set bit of the active mask at t.
    int myT = -1, myB = 0;
    int t_u = t0;
    while (__any((myT < 0) && act)) {
        const unsigned long long mask = __ballot(lenL > t_u);
        const int A = __popcll(mask);
        if ((myT < 0) && act && (k < S_run + A)) {
            const int myJ = k - S_run;
            // index of the myJ-th (0-based) set bit of mask
            int p = 0;
            if (__popcll(mask & 0xFFFFFFFFULL) <= myJ) p = 32;
#pragma unroll
            for (int w = 16; w; w >>= 1) {
                const unsigned long long low = (1ULL << (p + w)) - 1ULL;
                if (__popcll(mask & low) <= myJ) p += w;
            }
            myT = t_u;
            myB = p;
        }
        S_run += A;
        ++t_u;
        if (t_u > seq_len) break;  // safety net (unreachable for valid k)
    }

    float best = -FLT_MAX;
    int bidx = vocab;

    if (act && myT >= 0) {
        const int vmain = vocab & ~31;   // multiple of 32 floats (8 lanes x 4)
        const float* p = x + ((size_t)myT * batch + myB) * vocab + sl * 4;
        for (int base2 = 0; base2 < vmain; base2 += 32) {
            f32x4 v = *reinterpret_cast<const f32x4*>(p + base2);
            const int i0 = base2 + sl * 4;
#pragma unroll
            for (int j = 0; j < 4; ++j) {
                if (v[j] > best) { best = v[j]; bidx = i0 + j; }
            }
        }
        // Scalar tail (vocab % 32 != 0); tail indices exceed main indices,
        // strict '>' keeps the earlier occurrence; ties resolved in reduce.
        for (int i = vmain + sl; i < vocab; i += 8) {
            float v = x[((size_t)myT * batch + myB) * vocab + i];
            if (v > best) { best = v; bidx = i; }
        }
    }

    // 3-step xor reduce within each 8-lane group (all 8 tasks in parallel).
    // Larger value wins; on tie, lower index wins (first occurrence).
#pragma unroll
    for (int m = 1; m <= 4; m <<= 1) {
        float ov = __shfl_xor(best, m, 64);
        int oi = __shfl_xor(bidx, m, 64);
        if (ov > best || (ov == best && oi < bidx)) { best = ov; bidx = oi; }
    }

    if (act && myT >= 0 && sl == 0) {
        ml[(size_t)myB * seq_len + myT] = bidx;
    }
}

// Fallback (batch > 64): R8's interleaved-row argmax.
__global__ __launch_bounds__(256) void ctc_argmax_kernel(
    const float* __restrict__ x,
    int* __restrict__ ml,
    const int* __restrict__ lengths,
    int* __restrict__ tokens,
    int seq_len, int batch, int vocab) {
    const int nrows = seq_len * batch;

    const int gtid = blockIdx.x * blockDim.x + threadIdx.x;
    const int gstride = gridDim.x * blockDim.x;
    for (int i = gtid; i < nrows; i += gstride) tokens[i] = -1;

    const int lane = threadIdx.x & 63;
    const int wave = blockIdx.x * (blockDim.x >> 6) + (threadIdx.x >> 6);
    const int row0 = wave * 8;
    if (row0 >= nrows) return;

    const int g = lane >> 3;
    const int sl = lane & 7;
    const int row = row0 + g;

    bool act = false;
    int t = 0, b = 0;
    if (row < nrows) {
        t = row / batch;
        b = row - t * batch;
        act = (t < lengths[b]);
    }
    if (!__any(act)) return;

    float best = -FLT_MAX;
    int bidx = vocab;

    if (act) {
        const int vmain = vocab & ~31;
        const float* p = x + (size_t)row * vocab + sl * 4;
        for (int base = 0; base < vmain; base += 32) {
            f32x4 v = *reinterpret_cast<const f32x4*>(p + base);
            const int i0 = base + sl * 4;
#pragma unroll
            for (int j = 0; j < 4; ++j) {
                if (v[j] > best) { best = v[j]; bidx = i0 + j; }
            }
        }
        for (int i = vmain + sl; i < vocab; i += 8) {
            float v = x[(size_t)row * vocab + i];
            if (v > best) { best = v; bidx = i; }
        }
    }

#pragma unroll
    for (int m = 1; m <= 4; m <<= 1) {
        float ov = __shfl_xor(best, m, 64);
        int oi = __shfl_xor(bidx, m, 64);
        if (ov > best || (ov == best && oi < bidx)) { best = ov; bidx = oi; }
    }

    if (act && sl == 0) {
        ml[(size_t)b * seq_len + t] = bidx;
    }
}

// Kernel 2: per-batch removal of blanks and consecutive duplicates + left-pack.
// One block (512 threads) per batch element. tokens[] pre-filled with -1 by
// kernel 1. ml entries at t >= lengths[b] may be garbage; keep=false there,
// and prev at any kept t reads t-1 < len, so garbage never influences output.
__global__ __launch_bounds__(512) void ctc_compact_kernel(
    const int* __restrict__ ml,
    const int* __restrict__ lengths,
    const int* __restrict__ blank_ptr,
    int* __restrict__ tokens,
    int* __restrict__ out_lengths,
    int seq_len, int batch) {
    constexpr int MAXPER = 16;
    const int b = blockIdx.x;
    if (b >= batch) return;
    const int blank = *blank_ptr;
    const int len = lengths[b];
    const int* row = ml + (size_t)b * seq_len;
    int* out = tokens + (size_t)b * seq_len;

    const int tid = threadIdx.x;
    const int nthr = blockDim.x;
    const int per = (seq_len + nthr - 1) / nthr;  // 4 for 2048/512

    const int t0 = tid * per;
    int vals[MAXPER];
    unsigned keep_mask = 0;
    int cnt = 0;

    if (per == 4 && t0 + 4 <= seq_len && (seq_len & 3) == 0) {
        // Fast path: one aligned int4 load for this thread's 4 timesteps.
        i32x4 v4 = *reinterpret_cast<const i32x4*>(row + t0);
        int prev = (t0 == 0) ? -1 : row[t0 - 1];
#pragma unroll
        for (int j = 0; j < 4; ++j) {
            const int t = t0 + j;
            const int v = v4[j];
            const bool k = (t < len) && (v != blank) &&
                           (prev == blank || v != prev);
            vals[j] = v;
            if (k) { keep_mask |= (1u << j); ++cnt; }
            prev = v;
        }
    } else {
        int prev = (t0 == 0) ? -1 : ((t0 - 1 < seq_len) ? row[t0 - 1] : -1);
        for (int j = 0; j < per && j < MAXPER; ++j) {
            const int t = t0 + j;
            if (t >= seq_len) break;
            const int v = row[t];
            const bool k = (t < len) && (v != blank) &&
                           (prev == blank || v != prev);
            vals[j] = v;
            if (k) { keep_mask |= (1u << j); ++cnt; }
            prev = v;
        }
    }

    // Block-wide exclusive prefix sum of cnt (thread order).
    __shared__ int warp_sums[8];
    const int lane = tid & 63;
    const int wid = tid >> 6;
    int incl = cnt;
#pragma unroll
    for (int off = 1; off < 64; off <<= 1) {
        int n = __shfl_up(incl, off, 64);
        if (lane >= off) incl += n;
    }
    if (lane == 63) warp_sums[wid] = incl;
    __syncthreads();

    int wbase = 0;
    for (int w = 0; w < wid; ++w) wbase += warp_sums[w];
    int pos = wbase + incl - cnt;  // exclusive prefix for this thread

    for (int j = 0; j < per && j < MAXPER; ++j) {
        if (keep_mask & (1u << j)) out[pos++] = vals[j];
    }

    if (tid == 0) {
        int total = 0;
        const int nwaves = nthr >> 6;
        for (int w = 0; w < nwaves; ++w) total += warp_sums[w];
        out_lengths[b] = total;
    }
}

extern "C" void kernel_launch(void* const* d_in, const int* in_sizes, int n_in,
                              void* d_out, int out_size, void* d_ws, size_t ws_size,
                              hipStream_t stream) {
    const float* x = (const float*)d_in[0];
    const int* lengths = (const int*)d_in[1];
    const int* blank_ptr = (const int*)d_in[2];

    const int batch = in_sizes[1];
    const int seq_len = (out_size - batch) / batch;      // tokens is (batch, seq_len)
    const int vocab = in_sizes[0] / (seq_len * batch);

    int* tokens = (int*)d_out;                                  // (batch, seq_len)
    int* out_lengths = (int*)d_out + (size_t)batch * seq_len;   // (batch,)
    int* ml = (int*)d_ws;                                       // (batch, seq_len)

    // Kernel 1: 8 tasks per wave (8 lanes each), 4 waves per 256-thread block.
    // Grid sized for the worst case (all rows active); surplus waves retire
    // after a short prologue (total-reduce + exit).
    const int nrows = seq_len * batch;
    const int ntasks = (nrows + 7) / 8;
    const int waves_per_block = 4;
    const int blocks1 = (ntasks + waves_per_block - 1) / waves_per_block;
    if (batch <= 64) {
        ctc_argmax_dense<<<blocks1, waves_per_block * 64, 0, stream>>>(
            x, ml, lengths, tokens, seq_len, batch, vocab);
    } else {
        ctc_argmax_kernel<<<blocks1, waves_per_block * 64, 0, stream>>>(
            x, ml, lengths, tokens, seq_len, batch, vocab);
    }

    // Kernel 2: one block per batch element, 512 threads.
    ctc_compact_kernel<<<batch, 512, 0, stream>>>(
        ml, lengths, blank_ptr, tokens, out_lengths, seq_len, batch);
}

// Round 14
// 24.255 us; speedup vs baseline: 1.0485x; 1.0485x over previous
//
#include <hip/hip_runtime.h>
#include <hip/hip_bf16.h>
#include <float.h>

typedef float f32x4 __attribute__((ext_vector_type(4)));
typedef int i32x4 __attribute__((ext_vector_type(4)));

// Kernel 1 (dense): argmax over vocab for the ACTIVE (t,b) rows only.
// x layout: (seq_len, batch, vocab) row-major; row = t*batch + b.
// Active row k (b-major order: batch b contributes t=0..len[b]-1) is found
// via a per-wave prefix sum of lengths (batch<=64) + shuffle binary search.
// Wave->task mapping is XCD-swizzled (bijective, m204 variant) so each XCD
// group of waves owns a CONTIGUOUS chunk of dense task space (= contiguous
// memory region) -> per-XCD L2 locality + DRAM channel spread.
// Intra-wave: 8 tasks per wave, 8 lanes per task; 3-step __shfl_xor reduce.
// Output ml stored TRANSPOSED: ml[b*seq_len + t]. Also fills tokens with -1.
__global__ __launch_bounds__(256) void ctc_argmax_dense(
    const float* __restrict__ x,
    int* __restrict__ ml,
    const int* __restrict__ lengths,
    int* __restrict__ tokens,
    int seq_len, int batch, int vocab) {
    const int nrows = seq_len * batch;

    // -1 fill of tokens (batch*seq_len ints), grid-strided (measured free).
    const int gtid = blockIdx.x * blockDim.x + threadIdx.x;
    const int gstride = gridDim.x * blockDim.x;
    for (int i = gtid; i < nrows; i += gstride) tokens[i] = -1;

    const int lane = threadIdx.x & 63;
    const int wavesPerBlk = blockDim.x >> 6;
    const int orig = blockIdx.x * wavesPerBlk + (threadIdx.x >> 6);

    // Bijective XCD swizzle (8 XCDs): wave orig -> swz so that each residue
    // class (XCD round-robin) covers a contiguous task range.
    const int nw = gridDim.x * wavesPerBlk;
    const int q = nw >> 3, r = nw & 7;
    const int xcd = orig & 7, idx = orig >> 3;
    const int swz = (xcd < r ? xcd * (q + 1) : r * (q + 1) + (xcd - r) * q) + idx;
    const int k0 = swz * 8;

    // Inclusive prefix sum of lengths across lanes (batch <= 64).
    int myLen = (lane < batch) ? lengths[lane] : 0;
    int incl = myLen;
#pragma unroll
    for (int off = 1; off < 64; off <<= 1) {
        int n = __shfl_up(incl, off, 64);
        if (lane >= off) incl += n;
    }
    const int total = __shfl(incl, 63, 64);  // sum of lengths

    if (k0 >= total) return;  // inactive wave: retire after cheap prologue

    const int g = lane >> 3;    // task group 0..7
    const int sl = lane & 7;    // sub-lane within group
    const int k = k0 + g;       // this group's dense task id
    const bool act = (k < total);

    // Lower-bound search: b = #lanes with incl <= k (skips len==0 correctly).
    int pos = 0;
#pragma unroll
    for (int step = 32; step >= 1; step >>= 1) {
        const int probe = pos + step - 1;
        const int v = __shfl(incl, probe, 64);
        if (v <= k) pos += step;
    }
    const int b = pos;  // uniform within group (valid when act)
    const int baseRaw = __shfl(incl, (b == 0) ? 0 : b - 1, 64);
    const int base = (b == 0) ? 0 : baseRaw;
    const int t = k - base;     // 0 <= t < len[b] when act

    float best = -FLT_MAX;
    int bidx = vocab;

    if (act) {
        const int vmain = vocab & ~31;   // multiple of 32 floats (8 lanes x 4)
        const float* p = x + ((size_t)t * batch + b) * vocab + sl * 4;
        for (int base2 = 0; base2 < vmain; base2 += 32) {
            f32x4 v = *reinterpret_cast<const f32x4*>(p + base2);
            const int i0 = base2 + sl * 4;
#pragma unroll
            for (int j = 0; j < 4; ++j) {
                if (v[j] > best) { best = v[j]; bidx = i0 + j; }
            }
        }
        // Scalar tail (vocab % 32 != 0); tail indices exceed main indices,
        // strict '>' keeps the earlier occurrence; ties resolved in reduce.
        for (int i = vmain + sl; i < vocab; i += 8) {
            float v = x[((size_t)t * batch + b) * vocab + i];
            if (v > best) { best = v; bidx = i; }
        }
    }

    // 3-step xor reduce within each 8-lane group (all 8 tasks in parallel).
    // Larger value wins; on tie, lower index wins (first occurrence).
#pragma unroll
    for (int m = 1; m <= 4; m <<= 1) {
        float ov = __shfl_xor(best, m, 64);
        int oi = __shfl_xor(bidx, m, 64);
        if (ov > best || (ov == best && oi < bidx)) { best = ov; bidx = oi; }
    }

    if (act && sl == 0) {
        ml[(size_t)b * seq_len + t] = bidx;
    }
}

// Fallback (batch > 64): R8's interleaved-row argmax.
__global__ __launch_bounds__(256) void ctc_argmax_kernel(
    const float* __restrict__ x,
    int* __restrict__ ml,
    const int* __restrict__ lengths,
    int* __restrict__ tokens,
    int seq_len, int batch, int vocab) {
    const int nrows = seq_len * batch;

    const int gtid = blockIdx.x * blockDim.x + threadIdx.x;
    const int gstride = gridDim.x * blockDim.x;
    for (int i = gtid; i < nrows; i += gstride) tokens[i] = -1;

    const int lane = threadIdx.x & 63;
    const int wave = blockIdx.x * (blockDim.x >> 6) + (threadIdx.x >> 6);
    const int row0 = wave * 8;
    if (row0 >= nrows) return;

    const int g = lane >> 3;
    const int sl = lane & 7;
    const int row = row0 + g;

    bool act = false;
    int t = 0, b = 0;
    if (row < nrows) {
        t = row / batch;
        b = row - t * batch;
        act = (t < lengths[b]);
    }
    if (!__any(act)) return;

    float best = -FLT_MAX;
    int bidx = vocab;

    if (act) {
        const int vmain = vocab & ~31;
        const float* p = x + (size_t)row * vocab + sl * 4;
        for (int base = 0; base < vmain; base += 32) {
            f32x4 v = *reinterpret_cast<const f32x4*>(p + base);
            const int i0 = base + sl * 4;
#pragma unroll
            for (int j = 0; j < 4; ++j) {
                if (v[j] > best) { best = v[j]; bidx = i0 + j; }
            }
        }
        for (int i = vmain + sl; i < vocab; i += 8) {
            float v = x[(size_t)row * vocab + i];
            if (v > best) { best = v; bidx = i; }
        }
    }

#pragma unroll
    for (int m = 1; m <= 4; m <<= 1) {
        float ov = __shfl_xor(best, m, 64);
        int oi = __shfl_xor(bidx, m, 64);
        if (ov > best || (ov == best && oi < bidx)) { best = ov; bidx = oi; }
    }

    if (act && sl == 0) {
        ml[(size_t)b * seq_len + t] = bidx;
    }
}

// Kernel 2: per-batch removal of blanks and consecutive duplicates + left-pack.
// One block (512 threads) per batch element. tokens[] pre-filled with -1 by
// kernel 1. ml entries at t >= lengths[b] may be garbage; keep=false there,
// and prev at any kept t reads t-1 < len, so garbage never influences output.
__global__ __launch_bounds__(512) void ctc_compact_kernel(
    const int* __restrict__ ml,
    const int* __restrict__ lengths,
    const int* __restrict__ blank_ptr,
    int* __restrict__ tokens,
    int* __restrict__ out_lengths,
    int seq_len, int batch) {
    constexpr int MAXPER = 16;
    const int b = blockIdx.x;
    if (b >= batch) return;
    const int blank = *blank_ptr;
    const int len = lengths[b];
    const int* row = ml + (size_t)b * seq_len;
    int* out = tokens + (size_t)b * seq_len;

    const int tid = threadIdx.x;
    const int nthr = blockDim.x;
    const int per = (seq_len + nthr - 1) / nthr;  // 4 for 2048/512

    const int t0 = tid * per;
    int vals[MAXPER];
    unsigned keep_mask = 0;
    int cnt = 0;

    if (per == 4 && t0 + 4 <= seq_len && (seq_len & 3) == 0) {
        // Fast path: one aligned int4 load for this thread's 4 timesteps.
        i32x4 v4 = *reinterpret_cast<const i32x4*>(row + t0);
        int prev = (t0 == 0) ? -1 : row[t0 - 1];
#pragma unroll
        for (int j = 0; j < 4; ++j) {
            const int t = t0 + j;
            const int v = v4[j];
            const bool k = (t < len) && (v != blank) &&
                           (prev == blank || v != prev);
            vals[j] = v;
            if (k) { keep_mask |= (1u << j); ++cnt; }
            prev = v;
        }
    } else {
        int prev = (t0 == 0) ? -1 : ((t0 - 1 < seq_len) ? row[t0 - 1] : -1);
        for (int j = 0; j < per && j < MAXPER; ++j) {
            const int t = t0 + j;
            if (t >= seq_len) break;
            const int v = row[t];
            const bool k = (t < len) && (v != blank) &&
                           (prev == blank || v != prev);
            vals[j] = v;
            if (k) { keep_mask |= (1u << j); ++cnt; }
            prev = v;
        }
    }

    // Block-wide exclusive prefix sum of cnt (thread order).
    __shared__ int warp_sums[8];
    const int lane = tid & 63;
    const int wid = tid >> 6;
    int incl = cnt;
#pragma unroll
    for (int off = 1; off < 64; off <<= 1) {
        int n = __shfl_up(incl, off, 64);
        if (lane >= off) incl += n;
    }
    if (lane == 63) warp_sums[wid] = incl;
    __syncthreads();

    int wbase = 0;
    for (int w = 0; w < wid; ++w) wbase += warp_sums[w];
    int pos = wbase + incl - cnt;  // exclusive prefix for this thread

    for (int j = 0; j < per && j < MAXPER; ++j) {
        if (keep_mask & (1u << j)) out[pos++] = vals[j];
    }

    if (tid == 0) {
        int total = 0;
        const int nwaves = nthr >> 6;
        for (int w = 0; w < nwaves; ++w) total += warp_sums[w];
        out_lengths[b] = total;
    }
}

extern "C" void kernel_launch(void* const* d_in, const int* in_sizes, int n_in,
                              void* d_out, int out_size, void* d_ws, size_t ws_size,
                              hipStream_t stream) {
    const float* x = (const float*)d_in[0];
    const int* lengths = (const int*)d_in[1];
    const int* blank_ptr = (const int*)d_in[2];

    const int batch = in_sizes[1];
    const int seq_len = (out_size - batch) / batch;      // tokens is (batch, seq_len)
    const int vocab = in_sizes[0] / (seq_len * batch);

    int* tokens = (int*)d_out;                                  // (batch, seq_len)
    int* out_lengths = (int*)d_out + (size_t)batch * seq_len;   // (batch,)
    int* ml = (int*)d_ws;                                       // (batch, seq_len)

    // Kernel 1: 8 tasks per wave (8 lanes each), 4 waves per 256-thread block.
    // Grid sized for the worst case (all rows active); surplus waves retire
    // after a short prologue (prefix-sum + exit).
    const int nrows = seq_len * batch;
    const int ntasks = (nrows + 7) / 8;
    const int waves_per_block = 4;
    const int blocks1 = (ntasks + waves_per_block - 1) / waves_per_block;
    if (batch <= 64) {
        ctc_argmax_dense<<<blocks1, waves_per_block * 64, 0, stream>>>(
            x, ml, lengths, tokens, seq_len, batch, vocab);
    } else {
        ctc_argmax_kernel<<<blocks1, waves_per_block * 64, 0, stream>>>(
            x, ml, lengths, tokens, seq_len, batch, vocab);
    }

    // Kernel 2: one block per batch element, 512 threads.
    ctc_compact_kernel<<<batch, 512, 0, stream>>>(
        ml, lengths, blank_ptr, tokens, out_lengths, seq_len, batch);
}

// Round 15
// 20.347 us; speedup vs baseline: 1.2498x; 1.1921x over previous
//
#include <hip/hip_runtime.h>
#include <hip/hip_bf16.h>
#include <float.h>

typedef float f32x4 __attribute__((ext_vector_type(4)));
typedef int i32x4 __attribute__((ext_vector_type(4)));

// Kernel 1 (dense): argmax over vocab for the ACTIVE (t,b) rows only.
// x layout: (seq_len, batch, vocab) row-major; row = t*batch + b.
// Active row k (b-major order: batch b contributes t=0..len[b]-1) is found
// via a per-wave prefix sum of lengths (batch<=64) + shuffle binary search.
// Intra-wave: 8 tasks per wave, 8 lanes per task (lane>>3 = group, lane&7 =
// sub-lane); 3-step __shfl_xor reduce for all 8 tasks in parallel.
// Output ml stored TRANSPOSED: ml[b*seq_len + t]. Also fills tokens with -1.
__global__ __launch_bounds__(256) void ctc_argmax_dense(
    const float* __restrict__ x,
    int* __restrict__ ml,
    const int* __restrict__ lengths,
    int* __restrict__ tokens,
    int seq_len, int batch, int vocab) {
    const int nrows = seq_len * batch;

    // -1 fill of tokens (batch*seq_len ints), grid-strided (measured free).
    const int gtid = blockIdx.x * blockDim.x + threadIdx.x;
    const int gstride = gridDim.x * blockDim.x;
    for (int i = gtid; i < nrows; i += gstride) tokens[i] = -1;

    const int lane = threadIdx.x & 63;
    const int wave = blockIdx.x * (blockDim.x >> 6) + (threadIdx.x >> 6);

    // Inclusive prefix sum of lengths across lanes (batch <= 64).
    int myLen = (lane < batch) ? lengths[lane] : 0;
    int incl = myLen;
#pragma unroll
    for (int off = 1; off < 64; off <<= 1) {
        int n = __shfl_up(incl, off, 64);
        if (lane >= off) incl += n;
    }
    const int total = __shfl(incl, 63, 64);  // sum of lengths

    const int k0 = wave * 8;
    if (k0 >= total) return;  // inactive wave: retire after cheap prologue

    const int g = lane >> 3;    // task group 0..7
    const int sl = lane & 7;    // sub-lane within group
    const int k = k0 + g;       // this group's dense task id
    const bool act = (k < total);

    // Lower-bound search: b = #lanes with incl <= k (skips len==0 correctly).
    int pos = 0;
#pragma unroll
    for (int step = 32; step >= 1; step >>= 1) {
        const int probe = pos + step - 1;
        const int v = __shfl(incl, probe, 64);
        if (v <= k) pos += step;
    }
    const int b = pos;  // uniform within group (valid when act)
    const int baseRaw = __shfl(incl, (b == 0) ? 0 : b - 1, 64);
    const int base = (b == 0) ? 0 : baseRaw;
    const int t = k - base;     // 0 <= t < len[b] when act

    float best = -FLT_MAX;
    int bidx = vocab;

    if (act) {
        const int vmain = vocab & ~31;   // multiple of 32 floats (8 lanes x 4)
        const float* p = x + ((size_t)t * batch + b) * vocab + sl * 4;
        for (int base2 = 0; base2 < vmain; base2 += 32) {
            f32x4 v = *reinterpret_cast<const f32x4*>(p + base2);
            const int i0 = base2 + sl * 4;
#pragma unroll
            for (int j = 0; j < 4; ++j) {
                if (v[j] > best) { best = v[j]; bidx = i0 + j; }
            }
        }
        // Scalar tail (vocab % 32 != 0); tail indices exceed main indices,
        // strict '>' keeps the earlier occurrence; ties resolved in reduce.
        for (int i = vmain + sl; i < vocab; i += 8) {
            float v = x[((size_t)t * batch + b) * vocab + i];
            if (v > best) { best = v; bidx = i; }
        }
    }

    // 3-step xor reduce within each 8-lane group (all 8 tasks in parallel).
    // Larger value wins; on tie, lower index wins (first occurrence).
#pragma unroll
    for (int m = 1; m <= 4; m <<= 1) {
        float ov = __shfl_xor(best, m, 64);
        int oi = __shfl_xor(bidx, m, 64);
        if (ov > best || (ov == best && oi < bidx)) { best = ov; bidx = oi; }
    }

    if (act && sl == 0) {
        ml[(size_t)b * seq_len + t] = bidx;
    }
}

// Fallback (batch > 64): R8's interleaved-row argmax.
__global__ __launch_bounds__(256) void ctc_argmax_kernel(
    const float* __restrict__ x,
    int* __restrict__ ml,
    const int* __restrict__ lengths,
    int* __restrict__ tokens,
    int seq_len, int batch, int vocab) {
    const int nrows = seq_len * batch;

    const int gtid = blockIdx.x * blockDim.x + threadIdx.x;
    const int gstride = gridDim.x * blockDim.x;
    for (int i = gtid; i < nrows; i += gstride) tokens[i] = -1;

    const int lane = threadIdx.x & 63;
    const int wave = blockIdx.x * (blockDim.x >> 6) + (threadIdx.x >> 6);
    const int row0 = wave * 8;
    if (row0 >= nrows) return;

    const int g = lane >> 3;
    const int sl = lane & 7;
    const int row = row0 + g;

    bool act = false;
    int t = 0, b = 0;
    if (row < nrows) {
        t = row / batch;
        b = row - t * batch;
        act = (t < lengths[b]);
    }
    if (!__any(act)) return;

    float best = -FLT_MAX;
    int bidx = vocab;

    if (act) {
        const int vmain = vocab & ~31;
        const float* p = x + (size_t)row * vocab + sl * 4;
        for (int base = 0; base < vmain; base += 32) {
            f32x4 v = *reinterpret_cast<const f32x4*>(p + base);
            const int i0 = base + sl * 4;
#pragma unroll
            for (int j = 0; j < 4; ++j) {
                if (v[j] > best) { best = v[j]; bidx = i0 + j; }
            }
        }
        for (int i = vmain + sl; i < vocab; i += 8) {
            float v = x[(size_t)row * vocab + i];
            if (v > best) { best = v; bidx = i; }
        }
    }

#pragma unroll
    for (int m = 1; m <= 4; m <<= 1) {
        float ov = __shfl_xor(best, m, 64);
        int oi = __shfl_xor(bidx, m, 64);
        if (ov > best || (ov == best && oi < bidx)) { best = ov; bidx = oi; }
    }

    if (act && sl == 0) {
        ml[(size_t)b * seq_len + t] = bidx;
    }
}

// Kernel 2: per-batch removal of blanks and consecutive duplicates + left-pack.
// One block (512 threads) per batch element. tokens[] pre-filled with -1 by
// kernel 1. ml entries at t >= lengths[b] may be garbage; keep=false there,
// and prev at any kept t reads t-1 < len, so garbage never influences output.
__global__ __launch_bounds__(512) void ctc_compact_kernel(
    const int* __restrict__ ml,
    const int* __restrict__ lengths,
    const int* __restrict__ blank_ptr,
    int* __restrict__ tokens,
    int* __restrict__ out_lengths,
    int seq_len, int batch) {
    constexpr int MAXPER = 16;
    const int b = blockIdx.x;
    if (b >= batch) return;
    const int blank = *blank_ptr;
    const int len = lengths[b];
    const int* row = ml + (size_t)b * seq_len;
    int* out = tokens + (size_t)b * seq_len;

    const int tid = threadIdx.x;
    const int nthr = blockDim.x;
    const int per = (seq_len + nthr - 1) / nthr;  // 4 for 2048/512

    const int t0 = tid * per;
    int vals[MAXPER];
    unsigned keep_mask = 0;
    int cnt = 0;

    if (per == 4 && t0 + 4 <= seq_len && (seq_len & 3) == 0) {
        // Fast path: one aligned int4 load for this thread's 4 timesteps.
        i32x4 v4 = *reinterpret_cast<const i32x4*>(row + t0);
        int prev = (t0 == 0) ? -1 : row[t0 - 1];
#pragma unroll
        for (int j = 0; j < 4; ++j) {
            const int t = t0 + j;
            const int v = v4[j];
            const bool k = (t < len) && (v != blank) &&
                           (prev == blank || v != prev);
            vals[j] = v;
            if (k) { keep_mask |= (1u << j); ++cnt; }
            prev = v;
        }
    } else {
        int prev = (t0 == 0) ? -1 : ((t0 - 1 < seq_len) ? row[t0 - 1] : -1);
        for (int j = 0; j < per && j < MAXPER; ++j) {
            const int t = t0 + j;
            if (t >= seq_len) break;
            const int v = row[t];
            const bool k = (t < len) && (v != blank) &&
                           (prev == blank || v != prev);
            vals[j] = v;
            if (k) { keep_mask |= (1u << j); ++cnt; }
            prev = v;
        }
    }

    // Block-wide exclusive prefix sum of cnt (thread order).
    __shared__ int warp_sums[8];
    const int lane = tid & 63;
    const int wid = tid >> 6;
    int incl = cnt;
#pragma unroll
    for (int off = 1; off < 64; off <<= 1) {
        int n = __shfl_up(incl, off, 64);
        if (lane >= off) incl += n;
    }
    if (lane == 63) warp_sums[wid] = incl;
    __syncthreads();

    int wbase = 0;
    for (int w = 0; w < wid; ++w) wbase += warp_sums[w];
    int pos = wbase + incl - cnt;  // exclusive prefix for this thread

    for (int j = 0; j < per && j < MAXPER; ++j) {
        if (keep_mask & (1u << j)) out[pos++] = vals[j];
    }

    if (tid == 0) {
        int total = 0;
        const int nwaves = nthr >> 6;
        for (int w = 0; w < nwaves; ++w) total += warp_sums[w];
        out_lengths[b] = total;
    }
}

extern "C" void kernel_launch(void* const* d_in, const int* in_sizes, int n_in,
                              void* d_out, int out_size, void* d_ws, size_t ws_size,
                              hipStream_t stream) {
    const float* x = (const float*)d_in[0];
    const int* lengths = (const int*)d_in[1];
    const int* blank_ptr = (const int*)d_in[2];

    const int batch = in_sizes[1];
    const int seq_len = (out_size - batch) / batch;      // tokens is (batch, seq_len)
    const int vocab = in_sizes[0] / (seq_len * batch);

    int* tokens = (int*)d_out;                                  // (batch, seq_len)
    int* out_lengths = (int*)d_out + (size_t)batch * seq_len;   // (batch,)
    int* ml = (int*)d_ws;                                       // (batch, seq_len)

    // Kernel 1: 8 tasks per wave (8 lanes each), 4 waves per 256-thread block.
    // Grid sized for the worst case (all rows active); surplus waves retire
    // after a short prologue (prefix-sum + exit).
    const int nrows = seq_len * batch;
    const int ntasks = (nrows + 7) / 8;
    const int waves_per_block = 4;
    const int blocks1 = (ntasks + waves_per_block - 1) / waves_per_block;
    if (batch <= 64) {
        ctc_argmax_dense<<<blocks1, waves_per_block * 64, 0, stream>>>(
            x, ml, lengths, tokens, seq_len, batch, vocab);
    } else {
        ctc_argmax_kernel<<<blocks1, waves_per_block * 64, 0, stream>>>(
            x, ml, lengths, tokens, seq_len, batch, vocab);
    }

    // Kernel 2: one block per batch element, 512 threads.
    ctc_compact_kernel<<<batch, 512, 0, stream>>>(
        ml, lengths, blank_ptr, tokens, out_lengths, seq_len, batch);
}